// Round 1
// baseline (363.343 us; speedup 1.0000x reference)
//
#include <hip/hip_runtime.h>
#include <hip/hip_bf16.h>

// MultiSelfAttention: B=4, S=2048, D_MODEL=1024, H=16, Dk=64.
// Pipeline: cvt fp32->bf16 -> QKV proj GEMMs (bf16 MFMA, fp32 acc)
//           -> flash attention (online softmax, fp32 state)
//           -> O proj GEMM -> fp32 out.

typedef __attribute__((ext_vector_type(8))) short short8;
typedef __attribute__((ext_vector_type(4))) float f32x4;

#define DEV __device__ __forceinline__

DEV ushort f2bf(float f) {
  union { float f; unsigned u; } v; v.f = f;
  return (ushort)((v.u + 0x7fffu + ((v.u >> 16) & 1u)) >> 16);
}

DEV void gload_lds16(const void* g, void* lds) {
  __builtin_amdgcn_global_load_lds(
      (const __attribute__((address_space(1))) void*)g,
      (__attribute__((address_space(3))) void*)lds, 16, 0, 0);
}

// ---------------- fp32 -> bf16 convert ----------------
__global__ void cvt_kernel(const float* __restrict__ in, ushort* __restrict__ out, int n4) {
  int stride = gridDim.x * blockDim.x;
  for (int i = blockIdx.x * blockDim.x + threadIdx.x; i < n4; i += stride) {
    float4 v = ((const float4*)in)[i];
    ushort4 o;
    o.x = f2bf(v.x); o.y = f2bf(v.y); o.z = f2bf(v.z); o.w = f2bf(v.w);
    ((ushort4*)out)[i] = o;
  }
}

// ---------------- GEMM: C[m,n] = sum_k X[m,k]*W[n,k] + bias[n] ----------------
// X: [8192][1024] bf16 row-major, W: [1024][1024] bf16 row-major (N rows, K cols).
// MODE 0: out bf16 [b*16+h][s][d]   (Q,K head layout)
// MODE 1: out bf16 [b*16+h][d][s]   (V transposed layout)
// MODE 2: out fp32 [m][n]           (final output)
template<int MODE>
__global__ __launch_bounds__(256) void gemm_bt(
    const ushort* __restrict__ X, const ushort* __restrict__ W,
    const float* __restrict__ bias, void* __restrict__ out)
{
  constexpr int K = 1024, N = 1024;
  __shared__ __align__(16) ushort As[128 * 32];
  __shared__ __align__(16) ushort Bs[128 * 32];
  const int t = threadIdx.x;
  const int w = t >> 6, l = t & 63;
  const int bid = blockIdx.x;
  const int m0 = (bid >> 3) * 128, n0 = (bid & 7) * 128;
  const int wm = (w >> 1) * 64, wn = (w & 1) * 64;

  const f32x4 zero = {0.f, 0.f, 0.f, 0.f};
  f32x4 acc[4][4];
#pragma unroll
  for (int i = 0; i < 4; i++)
#pragma unroll
    for (int j = 0; j < 4; j++) acc[i][j] = zero;

  const int srow = l >> 2;          // row within 16-row chunk
  const int scolb = (l & 3) * 16;   // byte col within 64B row

  for (int kt = 0; kt < K; kt += 32) {
    __syncthreads();
#pragma unroll
    for (int c = w; c < 8; c += 4) {
      int row = c * 16 + srow;
      gload_lds16((const char*)X + ((size_t)(m0 + row) * K + kt) * 2 + scolb,
                  (char*)As + c * 1024);
      gload_lds16((const char*)W + ((size_t)(n0 + row) * K + kt) * 2 + scolb,
                  (char*)Bs + c * 1024);
    }
    __syncthreads();

    short8 af[4], bf[4];
#pragma unroll
    for (int i = 0; i < 4; i++) {
      af[i] = *(const short8*)((const char*)As + (wm + i * 16 + (l & 15)) * 64 + (l >> 4) * 16);
      bf[i] = *(const short8*)((const char*)Bs + (wn + i * 16 + (l & 15)) * 64 + (l >> 4) * 16);
    }
#pragma unroll
    for (int i = 0; i < 4; i++)
#pragma unroll
      for (int j = 0; j < 4; j++)
        acc[i][j] = __builtin_amdgcn_mfma_f32_16x16x32_bf16(af[i], bf[j], acc[i][j], 0, 0, 0);
  }

#pragma unroll
  for (int i = 0; i < 4; i++) {
    int mbase = m0 + wm + i * 16 + ((l >> 4) << 2);
#pragma unroll
    for (int j = 0; j < 4; j++) {
      int n = n0 + wn + j * 16 + (l & 15);
      float bv = bias[n];
#pragma unroll
      for (int r = 0; r < 4; r++) {
        int m = mbase + r;
        float v = acc[i][j][r] + bv;
        if (MODE == 2) {
          ((float*)out)[(size_t)m * N + n] = v;
        } else {
          int b = m >> 11, s = m & 2047;
          int h = n >> 6, d = n & 63;
          size_t off;
          if (MODE == 0) off = ((size_t)(b * 16 + h) * 2048 + s) * 64 + d;
          else           off = ((size_t)(b * 16 + h) * 64 + d) * 2048 + s;
          ((ushort*)out)[off] = f2bf(v);
        }
      }
    }
  }
}

// ---------------- Flash attention ----------------
// Qh,Kh: [64][2048][64] bf16.  Vt: [64][64][2048] bf16.  ctx: [4][2048][16][64] bf16.
// Block: 4 waves x 16 q-rows = 64 q-rows. KV tiles of 64.
__global__ __launch_bounds__(256) void attn_kernel(
    const ushort* __restrict__ Qh, const ushort* __restrict__ Kh,
    const ushort* __restrict__ Vt, ushort* __restrict__ ctx)
{
  __shared__ __align__(16) ushort Ks[64 * 64];
  __shared__ __align__(16) ushort Vs[64 * 64];
  __shared__ __align__(16) ushort Ps[4 * 16 * 64];
  const int t = threadIdx.x, w = t >> 6, l = t & 63;
  const int bh = blockIdx.y;
  const int q0 = blockIdx.x * 64 + w * 16;
  const ushort* Qb = Qh + (size_t)bh * 2048 * 64;
  const ushort* Kb = Kh + (size_t)bh * 2048 * 64;
  const ushort* Vb = Vt + (size_t)bh * 64 * 2048;

  // Hoist Q fragments (A operand: row=l&15, k=(l>>4)*8+j)
  short8 qa[2];
  {
    const ushort* p = Qb + (size_t)(q0 + (l & 15)) * 64 + (l >> 4) * 8;
    qa[0] = *(const short8*)(p);
    qa[1] = *(const short8*)(p + 32);
  }

  const f32x4 zero = {0.f, 0.f, 0.f, 0.f};
  f32x4 o_acc[4];
#pragma unroll
  for (int i = 0; i < 4; i++) o_acc[i] = zero;
  float mrow[4], lrow[4];
#pragma unroll
  for (int r = 0; r < 4; r++) { mrow[r] = -1e30f; lrow[r] = 0.f; }

  // staging: LDS linear dest, pre-swizzled global source (swz: byte ^= (row&7)<<4)
  const int srow8 = l >> 3;
  const int scolb = ((l & 7) ^ (l >> 3)) << 4;
  char* Pw = (char*)Ps + w * 2048;

  for (int kv0 = 0; kv0 < 2048; kv0 += 64) {
    __syncthreads();
#pragma unroll
    for (int c = w; c < 8; c += 4) {
      int row = c * 8 + srow8;
      gload_lds16((const char*)Kb + (size_t)(kv0 + row) * 128 + scolb, (char*)Ks + c * 1024);
      gload_lds16((const char*)Vb + (size_t)row * 4096 + (size_t)kv0 * 2 + scolb, (char*)Vs + c * 1024);
    }
    __syncthreads();

    // S = Q K^T * 1/8   (D: row=q=(l>>4)*4+r, col=kv=(l&15)+16*kvf)
    f32x4 sf[4];
#pragma unroll
    for (int kvf = 0; kvf < 4; kvf++) {
      int row = kvf * 16 + (l & 15);
      int sw = (row & 7) << 4;
      int base = row * 128 + (l >> 4) * 16;
      short8 b0 = *(const short8*)((const char*)Ks + (base ^ sw));
      short8 b1 = *(const short8*)((const char*)Ks + ((base + 64) ^ sw));
      f32x4 s = zero;
      s = __builtin_amdgcn_mfma_f32_16x16x32_bf16(qa[0], b0, s, 0, 0, 0);
      s = __builtin_amdgcn_mfma_f32_16x16x32_bf16(qa[1], b1, s, 0, 0, 0);
      sf[kvf] = s * 0.125f;
    }

    // online softmax: row stats across the 16 lanes of each row-group
    float fac[4];
#pragma unroll
    for (int r = 0; r < 4; r++) {
      float v = fmaxf(fmaxf(sf[0][r], sf[1][r]), fmaxf(sf[2][r], sf[3][r]));
#pragma unroll
      for (int off = 1; off < 16; off <<= 1) v = fmaxf(v, __shfl_xor(v, off));
      float mnew = fmaxf(mrow[r], v);
      fac[r] = __expf(mrow[r] - mnew);
      mrow[r] = mnew;
    }
    float rsum[4] = {0.f, 0.f, 0.f, 0.f};
#pragma unroll
    for (int kvf = 0; kvf < 4; kvf++)
#pragma unroll
      for (int r = 0; r < 4; r++) {
        float p = __expf(sf[kvf][r] - mrow[r]);
        sf[kvf][r] = p;
        rsum[r] += p;
      }
#pragma unroll
    for (int r = 0; r < 4; r++) {
      float v = rsum[r];
#pragma unroll
      for (int off = 1; off < 16; off <<= 1) v += __shfl_xor(v, off);
      lrow[r] = lrow[r] * fac[r] + v;
    }
#pragma unroll
    for (int i = 0; i < 4; i++) {
      f32x4 a = o_acc[i];
#pragma unroll
      for (int r = 0; r < 4; r++) a[r] *= fac[r];
      o_acc[i] = a;
    }

    // P -> bf16 -> per-wave LDS (swizzled), then reload in A-frag layout
#pragma unroll
    for (int kvf = 0; kvf < 4; kvf++)
#pragma unroll
      for (int r = 0; r < 4; r++) {
        int row = (l >> 4) * 4 + r;
        int col = kvf * 16 + (l & 15);
        int byte = (row * 128 + col * 2) ^ ((row & 7) << 4);
        *(ushort*)(Pw + byte) = f2bf(sf[kvf][r]);
      }
    asm volatile("s_waitcnt lgkmcnt(0)" ::: "memory");

    short8 pa[2];
    {
      int row = l & 15;
      int sw = (row & 7) << 4;
      int base = row * 128 + (l >> 4) * 16;
      pa[0] = *(const short8*)(Pw + (base ^ sw));
      pa[1] = *(const short8*)(Pw + ((base + 64) ^ sw));
    }
#pragma unroll
    for (int df = 0; df < 4; df++) {
      int row = df * 16 + (l & 15);
      int sw = (row & 7) << 4;
      int base = row * 128 + (l >> 4) * 16;
      short8 v0 = *(const short8*)((const char*)Vs + (base ^ sw));
      short8 v1 = *(const short8*)((const char*)Vs + ((base + 64) ^ sw));
      o_acc[df] = __builtin_amdgcn_mfma_f32_16x16x32_bf16(pa[0], v0, o_acc[df], 0, 0, 0);
      o_acc[df] = __builtin_amdgcn_mfma_f32_16x16x32_bf16(pa[1], v1, o_acc[df], 0, 0, 0);
    }
  }

  // epilogue: ctx[b][s][h][d] = o_acc / lrow
  const int b = bh >> 4, h = bh & 15;
#pragma unroll
  for (int r = 0; r < 4; r++) {
    int q = q0 + (l >> 4) * 4 + r;
    float inv = 1.f / lrow[r];
#pragma unroll
    for (int df = 0; df < 4; df++) {
      int d = df * 16 + (l & 15);
      size_t off = (((size_t)b * 2048 + q) * 16 + h) * 64 + d;
      ctx[off] = f2bf(o_acc[df][r] * inv);
    }
  }
}

extern "C" void kernel_launch(void* const* d_in, const int* in_sizes, int n_in,
                              void* d_out, int out_size, void* d_ws, size_t ws_size,
                              hipStream_t stream) {
  const float* q  = (const float*)d_in[0];
  const float* k  = (const float*)d_in[1];
  const float* v  = (const float*)d_in[2];
  const float* Wq = (const float*)d_in[3];
  const float* bq = (const float*)d_in[4];
  const float* Wk = (const float*)d_in[5];
  const float* bk = (const float*)d_in[6];
  const float* Wv = (const float*)d_in[7];
  const float* bv = (const float*)d_in[8];
  const float* Wo = (const float*)d_in[9];
  const float* bo = (const float*)d_in[10];

  const size_t MSZ = (size_t)8192 * 1024;  // activation elements
  const size_t WSZ = (size_t)1024 * 1024;  // weight elements
  char* ws = (char*)d_ws;
  ushort* Xbuf = (ushort*)ws;                 // 16 MB, reused for q/k/v bf16 and later ctx
  ushort* w16[4];
  w16[0] = Xbuf + MSZ;                        // Wq
  w16[1] = w16[0] + WSZ;                      // Wk
  w16[2] = w16[1] + WSZ;                      // Wv
  w16[3] = w16[2] + WSZ;                      // Wo
  ushort* Qhb = w16[3] + WSZ;                 // 16 MB
  ushort* Khb = Qhb + MSZ;                    // 16 MB
  ushort* Vtb = Khb + MSZ;                    // 16 MB
  ushort* ctx = Xbuf;                         // alias: free after gemm V consumed Xbuf
  // total ws use: 72 MB

  const float* Wsrc[4] = {Wq, Wk, Wv, Wo};
  for (int i = 0; i < 4; i++)
    cvt_kernel<<<512, 256, 0, stream>>>(Wsrc[i], w16[i], (int)(WSZ / 4));

  cvt_kernel<<<2048, 256, 0, stream>>>(q, Xbuf, (int)(MSZ / 4));
  gemm_bt<0><<<512, 256, 0, stream>>>(Xbuf, w16[0], bq, Qhb);
  cvt_kernel<<<2048, 256, 0, stream>>>(k, Xbuf, (int)(MSZ / 4));
  gemm_bt<0><<<512, 256, 0, stream>>>(Xbuf, w16[1], bk, Khb);
  cvt_kernel<<<2048, 256, 0, stream>>>(v, Xbuf, (int)(MSZ / 4));
  gemm_bt<1><<<512, 256, 0, stream>>>(Xbuf, w16[2], bv, Vtb);

  attn_kernel<<<dim3(32, 64), 256, 0, stream>>>(Qhb, Khb, Vtb, ctx);

  gemm_bt<2><<<512, 256, 0, stream>>>(ctx, w16[3], bo, (float*)d_out);
}

// Round 2
// 337.221 us; speedup vs baseline: 1.0775x; 1.0775x over previous
//
#include <hip/hip_runtime.h>
#include <hip/hip_bf16.h>

// MultiSelfAttention: B=4, S=2048, D_MODEL=1024, H=16, Dk=64.
// cvt fp32->bf16 -> QKV proj GEMMs (bf16 MFMA) -> flash attention
// (swapped QK^T, in-register P, defer-max) -> O proj GEMM -> fp32 out.

typedef __attribute__((ext_vector_type(8))) short short8;
typedef __attribute__((ext_vector_type(4))) float f32x4;

#define DEV __device__ __forceinline__

DEV ushort f2bf(float f) {
  union { float f; unsigned u; } v; v.f = f;
  return (ushort)((v.u + 0x7fffu + ((v.u >> 16) & 1u)) >> 16);
}

DEV void gload_lds16(const void* g, void* lds) {
  __builtin_amdgcn_global_load_lds(
      (const __attribute__((address_space(1))) void*)g,
      (__attribute__((address_space(3))) void*)lds, 16, 0, 0);
}

// ---------------- fp32 -> bf16 convert ----------------
__global__ void cvt_kernel(const float* __restrict__ in, ushort* __restrict__ out, int n4) {
  int stride = gridDim.x * blockDim.x;
  for (int i = blockIdx.x * blockDim.x + threadIdx.x; i < n4; i += stride) {
    float4 v = ((const float4*)in)[i];
    ushort4 o;
    o.x = f2bf(v.x); o.y = f2bf(v.y); o.z = f2bf(v.z); o.w = f2bf(v.w);
    ((ushort4*)out)[i] = o;
  }
}

// ---------------- GEMM: C[m,n] = sum_k X[m,k]*W[n,k] + bias[n] ----------------
// MODE 0: out bf16 [b*16+h][s][d]   (Q,K head layout)
// MODE 1: out bf16 [b*16+h][d][s]   (V transposed layout)
// MODE 2: out fp32 [m][n]           (final output)
template<int MODE>
__global__ __launch_bounds__(256) void gemm_bt(
    const ushort* __restrict__ X, const ushort* __restrict__ W,
    const float* __restrict__ bias, void* __restrict__ out)
{
  constexpr int K = 1024, N = 1024;
  __shared__ __align__(16) ushort As[128 * 32];
  __shared__ __align__(16) ushort Bs[128 * 32];
  const int t = threadIdx.x;
  const int w = t >> 6, l = t & 63;
  const int bid = blockIdx.x;
  const int m0 = (bid >> 3) * 128, n0 = (bid & 7) * 128;
  const int wm = (w >> 1) * 64, wn = (w & 1) * 64;

  const f32x4 zero = {0.f, 0.f, 0.f, 0.f};
  f32x4 acc[4][4];
#pragma unroll
  for (int i = 0; i < 4; i++)
#pragma unroll
    for (int j = 0; j < 4; j++) acc[i][j] = zero;

  const int srow = l >> 2;
  const int scolb = (l & 3) * 16;

  for (int kt = 0; kt < K; kt += 32) {
    __syncthreads();
#pragma unroll
    for (int c = w; c < 8; c += 4) {
      int row = c * 16 + srow;
      gload_lds16((const char*)X + ((size_t)(m0 + row) * K + kt) * 2 + scolb,
                  (char*)As + c * 1024);
      gload_lds16((const char*)W + ((size_t)(n0 + row) * K + kt) * 2 + scolb,
                  (char*)Bs + c * 1024);
    }
    __syncthreads();

    short8 af[4], bf[4];
#pragma unroll
    for (int i = 0; i < 4; i++) {
      af[i] = *(const short8*)((const char*)As + (wm + i * 16 + (l & 15)) * 64 + (l >> 4) * 16);
      bf[i] = *(const short8*)((const char*)Bs + (wn + i * 16 + (l & 15)) * 64 + (l >> 4) * 16);
    }
#pragma unroll
    for (int i = 0; i < 4; i++)
#pragma unroll
      for (int j = 0; j < 4; j++)
        acc[i][j] = __builtin_amdgcn_mfma_f32_16x16x32_bf16(af[i], bf[j], acc[i][j], 0, 0, 0);
  }

#pragma unroll
  for (int i = 0; i < 4; i++) {
    int mbase = m0 + wm + i * 16 + ((l >> 4) << 2);
#pragma unroll
    for (int j = 0; j < 4; j++) {
      int n = n0 + wn + j * 16 + (l & 15);
      float bv = bias[n];
#pragma unroll
      for (int r = 0; r < 4; r++) {
        int m = mbase + r;
        float v = acc[i][j][r] + bv;
        if (MODE == 2) {
          ((float*)out)[(size_t)m * N + n] = v;
        } else {
          int b = m >> 11, s = m & 2047;
          int h = n >> 6, d = n & 63;
          size_t off;
          if (MODE == 0) off = ((size_t)(b * 16 + h) * 2048 + s) * 64 + d;
          else           off = ((size_t)(b * 16 + h) * 64 + d) * 2048 + s;
          ((ushort*)out)[off] = f2bf(v);
        }
      }
    }
  }
}

// ---------------- Flash attention (swapped QK^T, in-register P) ----------------
// Qh,Kh: [64][2048][64] bf16.  Vt: [64][64][2048] bf16.  ctx: [4][2048][16][64] bf16.
// 4 waves x 16 q-rows. KV tiles of 64. Scores kept in log2 domain (Q pre-scaled).
__global__ __launch_bounds__(256) void attn_kernel(
    const ushort* __restrict__ Qh, const ushort* __restrict__ Kh,
    const ushort* __restrict__ Vt, ushort* __restrict__ ctx)
{
  __shared__ __align__(16) ushort Ks[64 * 64];
  __shared__ __align__(16) ushort Vs[64 * 64];
  const int t = threadIdx.x, w = t >> 6, l = t & 63;
  const int g = l >> 4, g1 = g >> 1, g0 = g & 1, qi = l & 15;
  const int bh = blockIdx.y;
  const int q0 = blockIdx.x * 64 + w * 16;
  const ushort* Qb = Qh + (size_t)bh * 2048 * 64;
  const ushort* Kb = Kh + (size_t)bh * 2048 * 64;
  const ushort* Vb = Vt + (size_t)bh * 64 * 2048;

  // Q fragment (B operand: col=q=l&15, k=d=g*8+j), pre-scaled by log2(e)/8
  short8 qa[2];
  {
    const ushort* p = Qb + (size_t)(q0 + qi) * 64 + g * 8;
    qa[0] = *(const short8*)(p);
    qa[1] = *(const short8*)(p + 32);
    const float SC = 0.18033688f;  // log2(e)/8
#pragma unroll
    for (int h = 0; h < 2; h++)
#pragma unroll
      for (int j = 0; j < 8; j++) {
        union { float f; unsigned u; } v;
        v.u = ((unsigned)(ushort)qa[h][j]) << 16;
        v.f *= SC;
        qa[h][j] = (short)f2bf(v.f);
      }
  }

  const f32x4 zero = {0.f, 0.f, 0.f, 0.f};
  f32x4 o_acc[4];
#pragma unroll
  for (int i = 0; i < 4; i++) o_acc[i] = zero;
  float m = -1e30f, lrow = 0.f;  // per-lane state for q = qi (log2 domain)

  // staging: LDS linear dest, pre-swizzled global source (swz: byte ^= (row&7)<<4)
  const int srow8 = l >> 3;
  const int scolb = ((l & 7) ^ (l >> 3)) << 4;

  for (int kv0 = 0; kv0 < 2048; kv0 += 64) {
    __syncthreads();
#pragma unroll
    for (int c = w; c < 8; c += 4) {
      int row = c * 8 + srow8;
      gload_lds16((const char*)Kb + (size_t)(kv0 + row) * 128 + scolb, (char*)Ks + c * 1024);
      gload_lds16((const char*)Vb + (size_t)row * 4096 + (size_t)kv0 * 2 + scolb, (char*)Vs + c * 1024);
    }
    __syncthreads();

    // S^T = K Q^T  (D: row=kv=16*kvf+g*4+r, col=q=qi), log2 domain
    f32x4 sf[4];
    __builtin_amdgcn_s_setprio(1);
#pragma unroll
    for (int kvf = 0; kvf < 4; kvf++) {
      int row = kvf * 16 + qi;
      int sw = (row & 7) << 4;
      int base = row * 128 + g * 16;
      short8 k0 = *(const short8*)((const char*)Ks + (base ^ sw));
      short8 k1 = *(const short8*)((const char*)Ks + ((base + 64) ^ sw));
      f32x4 s = zero;
      s = __builtin_amdgcn_mfma_f32_16x16x32_bf16(k0, qa[0], s, 0, 0, 0);
      s = __builtin_amdgcn_mfma_f32_16x16x32_bf16(k1, qa[1], s, 0, 0, 0);
      sf[kvf] = s;
    }
    __builtin_amdgcn_s_setprio(0);

    // online softmax, in-lane over 16 kv + 2 shfls across kv-groups
    float pmax = -1e30f;
#pragma unroll
    for (int kvf = 0; kvf < 4; kvf++)
#pragma unroll
      for (int r = 0; r < 4; r++) pmax = fmaxf(pmax, sf[kvf][r]);
    pmax = fmaxf(pmax, __shfl_xor(pmax, 16));
    pmax = fmaxf(pmax, __shfl_xor(pmax, 32));

    if (__any(pmax > m + 8.f)) {  // defer-max: rescale only when needed
      float mnew = fmaxf(m, pmax);
      float facq = exp2f(m - mnew);
      m = mnew;
      lrow *= facq;
#pragma unroll
      for (int r = 0; r < 4; r++) {
        float f = __shfl(facq, g * 4 + r);
#pragma unroll
        for (int df = 0; df < 4; df++) o_acc[df][r] *= f;
      }
    }

    float lsum = 0.f;
#pragma unroll
    for (int kvf = 0; kvf < 4; kvf++)
#pragma unroll
      for (int r = 0; r < 4; r++) {
        float p = exp2f(sf[kvf][r] - m);
        sf[kvf][r] = p;
        lsum += p;
      }
    lsum += __shfl_xor(lsum, 16);
    lsum += __shfl_xor(lsum, 32);
    lrow += lsum;

    // pack P to bf16 pairs: w8[kvf][p] = kv pair (16*kvf+4*g+2p, +1)
    unsigned w8[4][2];
#pragma unroll
    for (int kvf = 0; kvf < 4; kvf++)
#pragma unroll
      for (int p = 0; p < 2; p++)
        asm("v_cvt_pk_bf16_f32 %0, %1, %2"
            : "=v"(w8[kvf][p]) : "v"(sf[kvf][2 * p]), "v"(sf[kvf][2 * p + 1]));

    // redistribute to PV A-frag layout: lane needs kv = 32h + 8g + {0..7} for its q
    unsigned pw[2][4];
#pragma unroll
    for (int c2 = 0; c2 < 2; c2++)
#pragma unroll
      for (int c1 = 0; c1 < 2; c1++)
#pragma unroll
        for (int c0 = 0; c0 < 2; c0++) {
          unsigned prov = w8[2 * c2 + (c0 ^ g0)][c1];
          int src = (((g0 << 1) | (c0 ^ g1)) << 4) + qi;
          unsigned r = (unsigned)__shfl((int)prov, src);
          if (g1 == 0) pw[c2][(c0 << 1) | c1] = r;
          else         pw[c2][((c0 ^ 1) << 1) | c1] = r;
        }
    union { unsigned u[4]; short8 s; } pa0, pa1;
#pragma unroll
    for (int i = 0; i < 4; i++) { pa0.u[i] = pw[0][i]; pa1.u[i] = pw[1][i]; }

    // O += P V   (A=P: row=q=qi, k=kv; B=Vs[d][kv]: col=d=qi-dim, k=kv)
    __builtin_amdgcn_s_setprio(1);
#pragma unroll
    for (int df = 0; df < 4; df++) {
      int row = df * 16 + qi;
      int sw = (row & 7) << 4;
      int base = row * 128 + g * 16;
      short8 v0 = *(const short8*)((const char*)Vs + (base ^ sw));
      short8 v1 = *(const short8*)((const char*)Vs + ((base + 64) ^ sw));
      o_acc[df] = __builtin_amdgcn_mfma_f32_16x16x32_bf16(pa0.s, v0, o_acc[df], 0, 0, 0);
      o_acc[df] = __builtin_amdgcn_mfma_f32_16x16x32_bf16(pa1.s, v1, o_acc[df], 0, 0, 0);
    }
    __builtin_amdgcn_s_setprio(0);
  }

  // epilogue: ctx[b][s][h][d] = o_acc / l
  float linv = 1.f / lrow;
  const int b = bh >> 4, h = bh & 15;
#pragma unroll
  for (int r = 0; r < 4; r++) {
    int q = q0 + g * 4 + r;
    float inv = __shfl(linv, g * 4 + r);
#pragma unroll
    for (int df = 0; df < 4; df++) {
      int d = df * 16 + qi;
      size_t off = (((size_t)b * 2048 + q) * 16 + h) * 64 + d;
      ctx[off] = f2bf(o_acc[df][r] * inv);
    }
  }
}

extern "C" void kernel_launch(void* const* d_in, const int* in_sizes, int n_in,
                              void* d_out, int out_size, void* d_ws, size_t ws_size,
                              hipStream_t stream) {
  const float* q  = (const float*)d_in[0];
  const float* k  = (const float*)d_in[1];
  const float* v  = (const float*)d_in[2];
  const float* Wq = (const float*)d_in[3];
  const float* bq = (const float*)d_in[4];
  const float* Wk = (const float*)d_in[5];
  const float* bk = (const float*)d_in[6];
  const float* Wv = (const float*)d_in[7];
  const float* bv = (const float*)d_in[8];
  const float* Wo = (const float*)d_in[9];
  const float* bo = (const float*)d_in[10];

  const size_t MSZ = (size_t)8192 * 1024;
  const size_t WSZ = (size_t)1024 * 1024;
  char* ws = (char*)d_ws;
  ushort* Xbuf = (ushort*)ws;
  ushort* w16[4];
  w16[0] = Xbuf + MSZ;
  w16[1] = w16[0] + WSZ;
  w16[2] = w16[1] + WSZ;
  w16[3] = w16[2] + WSZ;
  ushort* Qhb = w16[3] + WSZ;
  ushort* Khb = Qhb + MSZ;
  ushort* Vtb = Khb + MSZ;
  ushort* ctx = Xbuf;

  const float* Wsrc[4] = {Wq, Wk, Wv, Wo};
  for (int i = 0; i < 4; i++)
    cvt_kernel<<<512, 256, 0, stream>>>(Wsrc[i], w16[i], (int)(WSZ / 4));

  cvt_kernel<<<2048, 256, 0, stream>>>(q, Xbuf, (int)(MSZ / 4));
  gemm_bt<0><<<512, 256, 0, stream>>>(Xbuf, w16[0], bq, Qhb);
  cvt_kernel<<<2048, 256, 0, stream>>>(k, Xbuf, (int)(MSZ / 4));
  gemm_bt<0><<<512, 256, 0, stream>>>(Xbuf, w16[1], bk, Khb);
  cvt_kernel<<<2048, 256, 0, stream>>>(v, Xbuf, (int)(MSZ / 4));
  gemm_bt<1><<<512, 256, 0, stream>>>(Xbuf, w16[2], bv, Vtb);

  attn_kernel<<<dim3(32, 64), 256, 0, stream>>>(Qhb, Khb, Vtb, ctx);

  gemm_bt<2><<<512, 256, 0, stream>>>(ctx, w16[3], bo, (float*)d_out);
}